// Round 10
// baseline (231.229 us; speedup 1.0000x reference)
//
#include <hip/hip_runtime.h>
#include <hip/hip_cooperative_groups.h>
#include <math.h>

namespace cg = cooperative_groups;

// ContrastiveLoss round 8 (third submit; prior two rounds were broker
// timeouts): single cooperative mega-kernel.
// Phases: P0 zero+normalize/split F -> P1 T tiles (hh + margin cold path) ->
// P2 validity/any_valid -> [P3 split E -> P4 S tiles, only if any row valid]
// -> P5 finalize. Grid-node overhead (~3-4us/node x 5 nodes) was the dominant
// residual over the fixed ~43us harness fill floor; this cuts it to 1 node.

constexpr int Bn = 4096;
constexpr int Dd = 512;
constexpr int Ff = 128;
constexpr int NT = (Bn / 128) * (Bn / 128 + 1) / 2;  // 528 triangle tiles
constexpr float MARGIN = 0.015625f;  // |T_hh - T_exact| < 2^-8; 4x safety

typedef __attribute__((ext_vector_type(8))) short bf16x8;
typedef __attribute__((ext_vector_type(4))) float f32x4;

__device__ __forceinline__ ushort f32_to_bf16(float x) {
    unsigned u = __float_as_uint(x);
    unsigned r = (u + 0x7FFFu + ((u >> 16) & 1u)) >> 16;  // RTNE
    return (ushort)r;
}
__device__ __forceinline__ float bf16_to_f32(ushort h) {
    return __uint_as_float(((unsigned)h) << 16);
}

__device__ __forceinline__ void tri_decode(int p, int& bi, int& bj) {
    bi = (int)((sqrtf(8.0f * (float)p + 1.0f) - 1.0f) * 0.5f);
    while ((bi + 1) * (bi + 2) / 2 <= p) ++bi;
    while (bi * (bi + 1) / 2 > p) --bi;
    bj = p - bi * (bi + 1) / 2;
}

// Stage a 128x64 bf16 tile via global_load_lds w=16; source pre-swizzled
// (rule #21), reads apply same XOR. Validated rounds 1-7: 0 bank conflicts.
__device__ __forceinline__ void stage_tile(const ushort* __restrict__ src, int stride,
                                           int k0, char* tile, int wave, int lane) {
    #pragma unroll
    for (int q = 0; q < 4; ++q) {
        int boff = wave * 4096 + q * 1024 + lane * 16;
        int row = boff >> 7;
        int cb = (boff & 127) ^ ((row & 7) << 4);
        const ushort* g = src + (size_t)row * stride + k0 + (cb >> 1);
        __builtin_amdgcn_global_load_lds(
            (const __attribute__((address_space(1))) void*)g,
            (__attribute__((address_space(3))) void*)(tile + wave * 4096 + q * 1024),
            16, 0, 0);
    }
}

__device__ __forceinline__ void mfma_step(f32x4 (&acc)[4][4], const char* At, const char* Bt,
                                          int wrow, int wcol, int lane) {
    #pragma unroll
    for (int ks = 0; ks < 2; ++ks) {
        bf16x8 a[4], b[4];
        int koff = ks * 64 + ((lane >> 4) << 4);
        #pragma unroll
        for (int m = 0; m < 4; ++m) {
            int row = wrow + m * 16 + (lane & 15);
            a[m] = *reinterpret_cast<const bf16x8*>(At + row * 128 + (koff ^ ((row & 7) << 4)));
        }
        #pragma unroll
        for (int n = 0; n < 4; ++n) {
            int row = wcol + n * 16 + (lane & 15);
            b[n] = *reinterpret_cast<const bf16x8*>(Bt + row * 128 + (koff ^ ((row & 7) << 4)));
        }
        #pragma unroll
        for (int m = 0; m < 4; ++m)
            #pragma unroll
            for (int n = 0; n < 4; ++n)
                acc[m][n] = __builtin_amdgcn_mfma_f32_16x16x32_bf16(a[m], b[n], acc[m][n], 0, 0, 0);
    }
}

__global__ __launch_bounds__(256, 2) void mega_kernel(
    const float* __restrict__ E, const float* __restrict__ SF,
    ushort* __restrict__ eh, ushort* __restrict__ el,
    ushort* __restrict__ fh, ushort* __restrict__ fl,
    float* __restrict__ row_sum, int* __restrict__ pos_cnt,
    int* __restrict__ any_valid, unsigned long long* __restrict__ posbits,
    float* __restrict__ out) {
    cg::grid_group grid = cg::this_grid();
    __shared__ __align__(16) char smem[65536];
    __shared__ int flagS;
    const int tid = threadIdx.x;
    const int bid = blockIdx.x;
    const int nb = gridDim.x;
    const int lane = tid & 63;
    const int wave = tid >> 6;
    const f32x4 z4 = {0.0f, 0.0f, 0.0f, 0.0f};

    // ---- P0: zero accumulators; L2-normalize + hi/lo split F ----
    for (int r = bid * 256 + tid; r < Bn; r += nb * 256) { row_sum[r] = 0.0f; pos_cnt[r] = 0; }
    if (bid == 0 && tid == 0) *any_valid = 0;
    for (int row = bid * 4 + wave; row < Bn; row += nb * 4) {
        float2 v = *reinterpret_cast<const float2*>(&SF[(size_t)row * Ff + lane * 2]);
        float ss = v.x * v.x + v.y * v.y;
        #pragma unroll
        for (int off = 32; off; off >>= 1) ss += __shfl_xor(ss, off, 64);
        float inv = 1.0f / fmaxf(sqrtf(ss), 1e-12f);
        float fx = v.x * inv, fy = v.y * inv;
        ushort hx = f32_to_bf16(fx), hy = f32_to_bf16(fy);
        ushort lx = f32_to_bf16(fx - bf16_to_f32(hx));
        ushort ly = f32_to_bf16(fy - bf16_to_f32(hy));
        ushort2 h; h.x = hx; h.y = hy;
        ushort2 l; l.x = lx; l.y = ly;
        *reinterpret_cast<ushort2*>(&fh[(size_t)row * Ff + lane * 2]) = h;
        *reinterpret_cast<ushort2*>(&fl[(size_t)row * Ff + lane * 2]) = l;
    }
    grid.sync();

    // ---- P1: T tiles (hh; hl+lh correction only within MARGIN of threshold) ----
    for (int p = bid; p < NT; p += nb) {
        __syncthreads();           // smem safe to reuse; order flagS across tiles
        if (tid == 0) flagS = 0;
        int bi, bj; tri_decode(p, bi, bj);
        const int ti = bi * 128, tj = bj * 128;
        const int wrow = (wave >> 1) * 64;
        const int wcol = (wave & 1) * 64;
        char* At = smem;
        char* Bt = smem + 16384;

        f32x4 acc[4][4];
        #pragma unroll
        for (int m = 0; m < 4; ++m)
            #pragma unroll
            for (int n = 0; n < 4; ++n) acc[m][n] = z4;

        for (int k0 = 0; k0 < Ff; k0 += 64) {
            stage_tile(fh + (size_t)ti * Ff, Ff, k0, At, wave, lane);
            stage_tile(fh + (size_t)tj * Ff, Ff, k0, Bt, wave, lane);
            __syncthreads();
            mfma_step(acc, At, Bt, wrow, wcol, lane);
            __syncthreads();
        }

        bool nr = false;
        #pragma unroll
        for (int m = 0; m < 4; ++m)
            #pragma unroll
            for (int n = 0; n < 4; ++n)
                #pragma unroll
                for (int r = 0; r < 4; ++r)
                    nr |= fabsf(acc[m][n][r] - 0.5f) < MARGIN;
        if (__any(nr)) { if (lane == 0) flagS = 1; }
        __syncthreads();

        if (flagS) {  // cold path: full 3-pass precision for this tile
            for (int k0 = 0; k0 < Ff; k0 += 64) {
                stage_tile(fh + (size_t)ti * Ff, Ff, k0, At, wave, lane);
                stage_tile(fl + (size_t)tj * Ff, Ff, k0, Bt, wave, lane);
                __syncthreads();
                mfma_step(acc, At, Bt, wrow, wcol, lane);
                __syncthreads();
            }
            for (int k0 = 0; k0 < Ff; k0 += 64) {
                stage_tile(fl + (size_t)ti * Ff, Ff, k0, At, wave, lane);
                stage_tile(fh + (size_t)tj * Ff, Ff, k0, Bt, wave, lane);
                __syncthreads();
                mfma_step(acc, At, Bt, wrow, wcol, lane);
                __syncthreads();
            }
        }

        unsigned long long pm = 0;
        #pragma unroll
        for (int m = 0; m < 4; ++m)
            #pragma unroll
            for (int n = 0; n < 4; ++n)
                #pragma unroll
                for (int r = 0; r < 4; ++r)
                    if (acc[m][n][r] > 0.5f) pm |= 1ull << (m * 16 + n * 4 + r);
        posbits[(size_t)p * 256 + tid] = pm;

        int colC[4] = {0, 0, 0, 0};
        #pragma unroll
        for (int m = 0; m < 4; ++m) {
            #pragma unroll
            for (int r = 0; r < 4; ++r) {
                int c = 0;
                int gi = ti + wrow + m * 16 + ((lane >> 4) << 2) + r;
                #pragma unroll
                for (int n = 0; n < 4; ++n) {
                    int gj = tj + wcol + n * 16 + (lane & 15);
                    bool pos = (pm >> (m * 16 + n * 4 + r)) & 1;
                    if (gi != gj && pos) {
                        c += 1;
                        if (bi != bj) colC[n] += 1;
                    }
                }
                #pragma unroll
                for (int off = 8; off; off >>= 1) c += __shfl_xor(c, off, 16);
                if ((lane & 15) == 0 && c) atomicAdd(&pos_cnt[gi], c);
            }
        }
        if (bi != bj) {
            #pragma unroll
            for (int n = 0; n < 4; ++n) {
                int c = colC[n];
                c += __shfl_xor(c, 16, 64);
                c += __shfl_xor(c, 32, 64);
                if ((lane >> 4) == 0 && c) {
                    int gj = tj + wcol + n * 16 + (lane & 15);
                    atomicAdd(&pos_cnt[gj], c);
                }
            }
        }
    }
    grid.sync();

    // ---- P2: validity -> any_valid ----
    {
        bool val = false;
        for (int r = bid * 256 + tid; r < Bn; r += nb * 256) {
            int pc = pos_cnt[r];
            val |= (pc > 0) && (pc < Bn - 1);
        }
        if (__any(val)) { if (lane == 0) atomicOr(any_valid, 1); }
    }
    grid.sync();

    int av = *any_valid;  // grid-uniform after sync
    if (av) {
        // ---- P3: split E into bf16 hi/lo ----
        for (int idx = bid * 256 + tid; idx < Bn * Dd / 4; idx += nb * 256) {
            size_t i = (size_t)idx * 4;
            float4 v = *reinterpret_cast<const float4*>(&E[i]);
            float c[4] = {v.x, v.y, v.z, v.w};
            ushort4 h, l;
            ushort hu[4], lu[4];
            #pragma unroll
            for (int j = 0; j < 4; ++j) {
                hu[j] = f32_to_bf16(c[j]);
                lu[j] = f32_to_bf16(c[j] - bf16_to_f32(hu[j]));
            }
            h.x = hu[0]; h.y = hu[1]; h.z = hu[2]; h.w = hu[3];
            l.x = lu[0]; l.y = lu[1]; l.z = lu[2]; l.w = lu[3];
            *reinterpret_cast<ushort4*>(&eh[i]) = h;
            *reinterpret_cast<ushort4*>(&el[i]) = l;
        }
        grid.sync();

        // ---- P4: S tiles (3-pass, per-tile gated on valid rows) ----
        for (int p = bid; p < NT; p += nb) {
            __syncthreads();
            if (tid == 0) flagS = 0;
            int bi, bj; tri_decode(p, bi, bj);
            const int ti = bi * 128, tj = bj * 128;
            __syncthreads();   // flagS=0 visible before any set
            int pc = (tid < 128) ? pos_cnt[ti + tid] : pos_cnt[tj + tid - 128];
            bool val = (pc > 0) && (pc < Bn - 1);
            if (__any(val)) { if (lane == 0) flagS = 1; }
            __syncthreads();
            if (!flagS) continue;

            char* Ah = smem;
            char* Al = smem + 16384;
            char* Bh = smem + 32768;
            char* Bl = smem + 49152;
            const int wrow = (wave >> 1) * 64;
            const int wcol = (wave & 1) * 64;

            f32x4 acc[4][4];
            #pragma unroll
            for (int m = 0; m < 4; ++m)
                #pragma unroll
                for (int n = 0; n < 4; ++n) acc[m][n] = z4;

            for (int k0 = 0; k0 < Dd; k0 += 64) {
                stage_tile(eh + (size_t)ti * Dd, Dd, k0, Ah, wave, lane);
                stage_tile(el + (size_t)ti * Dd, Dd, k0, Al, wave, lane);
                stage_tile(eh + (size_t)tj * Dd, Dd, k0, Bh, wave, lane);
                stage_tile(el + (size_t)tj * Dd, Dd, k0, Bl, wave, lane);
                __syncthreads();
                mfma_step(acc, Ah, Bh, wrow, wcol, lane);
                mfma_step(acc, Ah, Bl, wrow, wcol, lane);
                mfma_step(acc, Al, Bh, wrow, wcol, lane);
                __syncthreads();
            }

            unsigned long long pm = posbits[(size_t)p * 256 + tid];
            float colS[4] = {0, 0, 0, 0};
            #pragma unroll
            for (int m = 0; m < 4; ++m) {
                #pragma unroll
                for (int r = 0; r < 4; ++r) {
                    float s = 0.0f;
                    int gi = ti + wrow + m * 16 + ((lane >> 4) << 2) + r;
                    #pragma unroll
                    for (int n = 0; n < 4; ++n) {
                        int gj = tj + wcol + n * 16 + (lane & 15);
                        if (gi != gj) {
                            float S = acc[m][n][r] * 10.0f;
                            bool pos = (pm >> (m * 16 + n * 4 + r)) & 1;
                            float x = pos ? -S : S;
                            float sp = fmaxf(x, 0.0f) + log1pf(expf(-fabsf(x)));
                            s += sp;
                            if (bi != bj) colS[n] += sp;
                        }
                    }
                    #pragma unroll
                    for (int off = 8; off; off >>= 1) s += __shfl_xor(s, off, 16);
                    if ((lane & 15) == 0) atomicAdd(&row_sum[gi], s);
                }
            }
            if (bi != bj) {
                #pragma unroll
                for (int n = 0; n < 4; ++n) {
                    float s = colS[n];
                    s += __shfl_xor(s, 16, 64);
                    s += __shfl_xor(s, 32, 64);
                    if ((lane >> 4) == 0) {
                        int gj = tj + wcol + n * 16 + (lane & 15);
                        atomicAdd(&row_sum[gj], s);
                    }
                }
            }
        }
        grid.sync();
    }

    // ---- P5: finalize (block 0) ----
    if (bid == 0) {
        float* ssum = (float*)smem;
        int* scnt = (int*)(smem + 1024);
        float ls = 0.0f;
        int lc = 0;
        for (int r = tid; r < Bn; r += 256) {
            int pz = pos_cnt[r];
            if (pz > 0 && pz < Bn - 1) {
                ls += row_sum[r] / (float)(Bn - 1);
                lc += 1;
            }
        }
        ssum[tid] = ls;
        scnt[tid] = lc;
        __syncthreads();
        for (int s = 128; s; s >>= 1) {
            if (tid < s) {
                ssum[tid] += ssum[tid + s];
                scnt[tid] += scnt[tid + s];
            }
            __syncthreads();
        }
        if (tid == 0) {
            float nv = fmaxf((float)scnt[0], 1.0f);
            out[0] = ssum[0] / nv;
        }
    }
}

extern "C" void kernel_launch(void* const* d_in, const int* in_sizes, int n_in,
                              void* d_out, int out_size, void* d_ws, size_t ws_size,
                              hipStream_t stream) {
    const float* E = (const float*)d_in[0];   // [4096,512] f32
    const float* SF = (const float*)d_in[1];  // [4096,128] f32
    float* out = (float*)d_out;

    // ws: eh(4M) el(4M) fh(1M) fl(1M) row_sum(16K) pos_cnt(16K) any_valid posbits(1.08M)
    ushort* eh = (ushort*)d_ws;
    ushort* el = eh + (size_t)Bn * Dd;
    ushort* fh = el + (size_t)Bn * Dd;
    ushort* fl = fh + (size_t)Bn * Ff;
    float* row_sum = (float*)(fl + (size_t)Bn * Ff);
    int* pos_cnt = (int*)(row_sum + Bn);
    int* any_valid = pos_cnt + Bn;
    unsigned long long* posbits =
        (unsigned long long*)(((size_t)(any_valid + 16) + 15) & ~15ull);

    // __launch_bounds__(256,2) guarantees 2 blocks/CU (64KB LDS of 160KB);
    // 256 CUs x 2 = 512 co-resident blocks. No host queries during capture.
    constexpr int GRID = 512;

    void* args[] = {(void*)&E, (void*)&SF, (void*)&eh, (void*)&el,
                    (void*)&fh, (void*)&fl, (void*)&row_sum, (void*)&pos_cnt,
                    (void*)&any_valid, (void*)&posbits, (void*)&out};
    hipLaunchCooperativeKernel((void*)mega_kernel, dim3(GRID), dim3(256),
                               args, 0, stream);
}

// Round 11
// 109.133 us; speedup vs baseline: 2.1188x; 2.1188x over previous
//
#include <hip/hip_runtime.h>
#include <math.h>

// ContrastiveLoss round 11: revert from cooperative (grid.sync ~50us each on
// MI355X, round-10 lesson) to 3 stream-ordered kernels:
//  A t_fused : per-tile in-LDS normalize+split of F (L2-redundant, cheap) +
//              hh MFMA + margin cold-path; writes posbits + cnt[4096][32]
//              (unique-writer, no atomics/pre-zero) + zeroes row_sum.
//  C s_kernel: gated on cnt row sums; cold path converts E on the fly.
//  D finalize: sums cnt + row_sum -> loss.

constexpr int Bn = 4096;
constexpr int Dd = 512;
constexpr int Ff = 128;
constexpr int NB = Bn / 128;                 // 32 row blocks
constexpr int NT = NB * (NB + 1) / 2;        // 528 triangle tiles
constexpr float MARGIN = 0.015625f;          // |T_hh - T_3pass| < 2^-8; 4x safety

typedef __attribute__((ext_vector_type(8))) short bf16x8;
typedef __attribute__((ext_vector_type(4))) float f32x4;

__device__ __forceinline__ ushort f32_to_bf16(float x) {
    unsigned u = __float_as_uint(x);
    unsigned r = (u + 0x7FFFu + ((u >> 16) & 1u)) >> 16;  // RTNE
    return (ushort)r;
}
__device__ __forceinline__ float bf16_to_f32(ushort h) {
    return __uint_as_float(((unsigned)h) << 16);
}

__device__ __forceinline__ void tri_decode(int p, int& bi, int& bj) {
    bi = (int)((sqrtf(8.0f * (float)p + 1.0f) - 1.0f) * 0.5f);
    while ((bi + 1) * (bi + 2) / 2 <= p) ++bi;
    while (bi * (bi + 1) / 2 > p) --bi;
    bj = p - bi * (bi + 1) / 2;
}

// mfma over one 64-col chunk buffer (row stride 128B, XOR-swizzled layout).
// Validated rounds 1-7: 0 bank conflicts.
__device__ __forceinline__ void mfma_step(f32x4 (&acc)[4][4], const char* At, const char* Bt,
                                          int wrow, int wcol, int lane) {
    #pragma unroll
    for (int ks = 0; ks < 2; ++ks) {
        bf16x8 a[4], b[4];
        int koff = ks * 64 + ((lane >> 4) << 4);
        #pragma unroll
        for (int m = 0; m < 4; ++m) {
            int row = wrow + m * 16 + (lane & 15);
            a[m] = *reinterpret_cast<const bf16x8*>(At + row * 128 + (koff ^ ((row & 7) << 4)));
        }
        #pragma unroll
        for (int n = 0; n < 4; ++n) {
            int row = wcol + n * 16 + (lane & 15);
            b[n] = *reinterpret_cast<const bf16x8*>(Bt + row * 128 + (koff ^ ((row & 7) << 4)));
        }
        #pragma unroll
        for (int m = 0; m < 4; ++m)
            #pragma unroll
            for (int n = 0; n < 4; ++n)
                acc[m][n] = __builtin_amdgcn_mfma_f32_16x16x32_bf16(a[m], b[n], acc[m][n], 0, 0, 0);
    }
}

// Normalize+split 128 F rows [rowBase..rowBase+128) into buf (2 chunk buffers
// of [128 rows][64 cols bf16], XOR-swizzled). Whole wave per row; lane l holds
// cols 2l,2l+1 (lanes 0-31 -> chunk0, 32-63 -> chunk1). lo=false: hi part.
__device__ __forceinline__ void norm_stage(const float* __restrict__ SF, int rowBase,
                                           bool lo, char* buf, int wave, int lane) {
    #pragma unroll 4
    for (int i = 0; i < 32; ++i) {
        int lr = wave * 32 + i;   // local row 0..127
        float2 v = *reinterpret_cast<const float2*>(&SF[(size_t)(rowBase + lr) * Ff + lane * 2]);
        float ss = v.x * v.x + v.y * v.y;
        #pragma unroll
        for (int off = 32; off; off >>= 1) ss += __shfl_xor(ss, off, 64);
        float inv = 1.0f / fmaxf(sqrtf(ss), 1e-12f);
        float fx = v.x * inv, fy = v.y * inv;
        ushort hx = f32_to_bf16(fx), hy = f32_to_bf16(fy);
        ushort ox = hx, oy = hy;
        if (lo) {
            ox = f32_to_bf16(fx - bf16_to_f32(hx));
            oy = f32_to_bf16(fy - bf16_to_f32(hy));
        }
        int cb = (4 * lane) & 127;                 // col byte within chunk
        int d = cb ^ ((lr & 7) << 4);              // swizzled byte
        ushort2 o; o.x = ox; o.y = oy;
        *reinterpret_cast<ushort2*>(buf + (lane >> 5) * 16384 + lr * 128 + d) = o;
    }
}

// A: fused normalize + T tiles. cnt[row][otherBlock] unique-writer counts.
__global__ __launch_bounds__(256, 2) void t_fused_kernel(
    const float* __restrict__ SF, unsigned long long* __restrict__ posbits,
    int* __restrict__ cnt, float* __restrict__ row_sum) {
    __shared__ __align__(16) char smem[65536];
    __shared__ int flagS;
    __shared__ int rowCnt[128];
    __shared__ int colCnt[128];

    const int tid = threadIdx.x;
    const int lane = tid & 63;
    const int wave = tid >> 6;

    if (blockIdx.x < 16) row_sum[blockIdx.x * 256 + tid] = 0.0f;  // pre-S zero
    if (tid == 0) flagS = 0;

    int bi, bj; tri_decode(blockIdx.x, bi, bj);
    const int ti = bi * 128, tj = bj * 128;
    const int wrow = (wave >> 1) * 64;
    const int wcol = (wave & 1) * 64;
    char* Abuf = smem;            // chunks at +0, +16384
    char* Bbuf = smem + 32768;    // chunks at +0, +16384

    f32x4 acc[4][4];
    const f32x4 z4 = {0.0f, 0.0f, 0.0f, 0.0f};
    #pragma unroll
    for (int m = 0; m < 4; ++m)
        #pragma unroll
        for (int n = 0; n < 4; ++n) acc[m][n] = z4;

    // hh (hot)
    norm_stage(SF, ti, false, Abuf, wave, lane);
    norm_stage(SF, tj, false, Bbuf, wave, lane);
    __syncthreads();
    mfma_step(acc, Abuf, Bbuf, wrow, wcol, lane);
    mfma_step(acc, Abuf + 16384, Bbuf + 16384, wrow, wcol, lane);

    bool nr = false;
    #pragma unroll
    for (int m = 0; m < 4; ++m)
        #pragma unroll
        for (int n = 0; n < 4; ++n)
            #pragma unroll
            for (int r = 0; r < 4; ++r)
                nr |= fabsf(acc[m][n][r] - 0.5f) < MARGIN;
    if (__any(nr)) { if (lane == 0) flagS = 1; }
    __syncthreads();

    if (flagS) {  // cold path: add hl + lh terms (full 3-pass precision)
        norm_stage(SF, tj, true, Bbuf, wave, lane);   // B <- lo
        __syncthreads();
        mfma_step(acc, Abuf, Bbuf, wrow, wcol, lane);               // Ah*Bl
        mfma_step(acc, Abuf + 16384, Bbuf + 16384, wrow, wcol, lane);
        __syncthreads();
        norm_stage(SF, ti, true, Abuf, wave, lane);   // A <- lo
        norm_stage(SF, tj, false, Bbuf, wave, lane);  // B <- hi
        __syncthreads();
        mfma_step(acc, Abuf, Bbuf, wrow, wcol, lane);               // Al*Bh
        mfma_step(acc, Abuf + 16384, Bbuf + 16384, wrow, wcol, lane);
    }

    // positive bits
    unsigned long long pm = 0;
    #pragma unroll
    for (int m = 0; m < 4; ++m)
        #pragma unroll
        for (int n = 0; n < 4; ++n)
            #pragma unroll
            for (int r = 0; r < 4; ++r)
                if (acc[m][n][r] > 0.5f) pm |= 1ull << (m * 16 + n * 4 + r);
    posbits[(size_t)blockIdx.x * 256 + tid] = pm;

    // LDS count aggregation (zero atomics for zero positives)
    if (tid < 128) rowCnt[tid] = 0; else colCnt[tid - 128] = 0;
    __syncthreads();
    #pragma unroll
    for (int m = 0; m < 4; ++m) {
        #pragma unroll
        for (int r = 0; r < 4; ++r) {
            int lrow = wrow + m * 16 + ((lane >> 4) << 2) + r;
            int gi = ti + lrow;
            #pragma unroll
            for (int n = 0; n < 4; ++n) {
                int lcol = wcol + n * 16 + (lane & 15);
                int gj = tj + lcol;
                if (gi != gj && ((pm >> (m * 16 + n * 4 + r)) & 1)) {
                    atomicAdd(&rowCnt[lrow], 1);
                    atomicAdd(&colCnt[lcol], 1);
                }
            }
        }
    }
    __syncthreads();
    if (tid < 128) cnt[(size_t)(ti + tid) * NB + bj] = rowCnt[tid];
    else if (bi != bj) cnt[(size_t)(tj + tid - 128) * NB + bi] = colCnt[tid - 128];
}

// Convert+stage one 64-col K-chunk of E rows [rowBase..+128) into hi/lo
// swizzled chunk buffers (cold path only).
__device__ __forceinline__ void stage_conv(const float* __restrict__ E, int rowBase,
                                           int k0, char* Hbuf, char* Lbuf,
                                           int wave, int lane) {
    #pragma unroll
    for (int q = 0; q < 4; ++q) {
        int boff = wave * 4096 + q * 1024 + lane * 16;
        int row = boff >> 7;
        int d = boff & 127;
        int cb = d ^ ((row & 7) << 4);   // source col byte (bf16) within chunk
        const float* src = &E[(size_t)(rowBase + row) * Dd + k0 + (cb >> 1)];
        float4 v0 = *reinterpret_cast<const float4*>(src);
        float4 v1 = *reinterpret_cast<const float4*>(src + 4);
        float c[8] = {v0.x, v0.y, v0.z, v0.w, v1.x, v1.y, v1.z, v1.w};
        bf16x8 hv, lv;
        #pragma unroll
        for (int j = 0; j < 8; ++j) {
            ushort h = f32_to_bf16(c[j]);
            hv[j] = (short)h;
            lv[j] = (short)f32_to_bf16(c[j] - bf16_to_f32(h));
        }
        *reinterpret_cast<bf16x8*>(Hbuf + boff) = hv;
        *reinterpret_cast<bf16x8*>(Lbuf + boff) = lv;
    }
}

// C: S tiles, gated on cnt row sums; on-the-fly E conversion when active.
__global__ __launch_bounds__(256, 2) void s_kernel(
    const float* __restrict__ E, const unsigned long long* __restrict__ posbits,
    const int* __restrict__ cnt, float* __restrict__ row_sum) {
    __shared__ __align__(16) char smem[65536];
    __shared__ int go;
    const int tid = threadIdx.x;
    int bi, bj; tri_decode(blockIdx.x, bi, bj);
    const int ti = bi * 128, tj = bj * 128;

    if (tid == 0) go = 0;
    __syncthreads();
    {
        int r = (tid < 128) ? (ti + tid) : (tj + tid - 128);
        const int4* c4 = reinterpret_cast<const int4*>(&cnt[(size_t)r * NB]);
        int pc = 0;
        #pragma unroll
        for (int q = 0; q < 8; ++q) {
            int4 v = c4[q];
            pc += v.x + v.y + v.z + v.w;
        }
        bool val = (pc > 0) && (pc < Bn - 1);
        if (__any(val)) { if ((tid & 63) == 0) go = 1; }
    }
    __syncthreads();
    if (!go) return;

    const int lane = tid & 63;
    const int wave = tid >> 6;
    const int wrow = (wave >> 1) * 64;
    const int wcol = (wave & 1) * 64;
    char* Ah = smem;
    char* Al = smem + 16384;
    char* Bh = smem + 32768;
    char* Bl = smem + 49152;

    f32x4 acc[4][4];
    const f32x4 z4 = {0.0f, 0.0f, 0.0f, 0.0f};
    #pragma unroll
    for (int m = 0; m < 4; ++m)
        #pragma unroll
        for (int n = 0; n < 4; ++n) acc[m][n] = z4;

    for (int k0 = 0; k0 < Dd; k0 += 64) {
        __syncthreads();   // previous chunk fully consumed
        stage_conv(E, ti, k0, Ah, Al, wave, lane);
        stage_conv(E, tj, k0, Bh, Bl, wave, lane);
        __syncthreads();
        mfma_step(acc, Ah, Bh, wrow, wcol, lane);
        mfma_step(acc, Ah, Bl, wrow, wcol, lane);
        mfma_step(acc, Al, Bh, wrow, wcol, lane);
    }

    unsigned long long pm = posbits[(size_t)blockIdx.x * 256 + tid];
    float colS[4] = {0, 0, 0, 0};
    #pragma unroll
    for (int m = 0; m < 4; ++m) {
        #pragma unroll
        for (int r = 0; r < 4; ++r) {
            float s = 0.0f;
            int gi = ti + wrow + m * 16 + ((lane >> 4) << 2) + r;
            #pragma unroll
            for (int n = 0; n < 4; ++n) {
                int gj = tj + wcol + n * 16 + (lane & 15);
                if (gi != gj) {
                    float S = acc[m][n][r] * 10.0f;            // /TEMPERATURE
                    bool pos = (pm >> (m * 16 + n * 4 + r)) & 1;
                    float x = pos ? -S : S;
                    float sp = fmaxf(x, 0.0f) + log1pf(expf(-fabsf(x)));  // softplus
                    s += sp;
                    if (bi != bj) colS[n] += sp;
                }
            }
            #pragma unroll
            for (int off = 8; off; off >>= 1) s += __shfl_xor(s, off, 16);
            if ((lane & 15) == 0) atomicAdd(&row_sum[gi], s);
        }
    }
    if (bi != bj) {
        #pragma unroll
        for (int n = 0; n < 4; ++n) {
            float s = colS[n];
            s += __shfl_xor(s, 16, 64);
            s += __shfl_xor(s, 32, 64);
            if ((lane >> 4) == 0) {
                int gj = tj + wcol + n * 16 + (lane & 15);
                atomicAdd(&row_sum[gj], s);
            }
        }
    }
}

// D: finalize — per-row counts from cnt, mean over valid rows.
__global__ __launch_bounds__(256) void finalize_kernel(
    const float* __restrict__ row_sum, const int* __restrict__ cnt,
    float* __restrict__ out) {
    __shared__ float ssum[256];
    __shared__ int scnt[256];
    float ls = 0.0f;
    int lc = 0;
    for (int r = threadIdx.x; r < Bn; r += 256) {
        const int4* c4 = reinterpret_cast<const int4*>(&cnt[(size_t)r * NB]);
        int pc = 0;
        #pragma unroll
        for (int q = 0; q < 8; ++q) {
            int4 v = c4[q];
            pc += v.x + v.y + v.z + v.w;
        }
        if (pc > 0 && pc < Bn - 1) {
            ls += row_sum[r] / (float)(Bn - 1);
            lc += 1;
        }
    }
    ssum[threadIdx.x] = ls;
    scnt[threadIdx.x] = lc;
    __syncthreads();
    for (int s = 128; s; s >>= 1) {
        if (threadIdx.x < s) {
            ssum[threadIdx.x] += ssum[threadIdx.x + s];
            scnt[threadIdx.x] += scnt[threadIdx.x + s];
        }
        __syncthreads();
    }
    if (threadIdx.x == 0) {
        float nv = fmaxf((float)scnt[0], 1.0f);
        out[0] = ssum[0] / nv;
    }
}

extern "C" void kernel_launch(void* const* d_in, const int* in_sizes, int n_in,
                              void* d_out, int out_size, void* d_ws, size_t ws_size,
                              hipStream_t stream) {
    const float* E = (const float*)d_in[0];   // [4096,512] f32
    const float* SF = (const float*)d_in[1];  // [4096,128] f32
    float* out = (float*)d_out;

    // ws: cnt[4096*32] int (512K) | row_sum[4096] f32 (16K) | posbits (1.06M)
    int* cnt = (int*)d_ws;
    float* row_sum = (float*)(cnt + (size_t)Bn * NB);
    unsigned long long* posbits =
        (unsigned long long*)(((size_t)(row_sum + Bn) + 15) & ~15ull);

    t_fused_kernel<<<NT, 256, 0, stream>>>(SF, posbits, cnt, row_sum);
    s_kernel<<<NT, 256, 0, stream>>>(E, posbits, cnt, row_sum);
    finalize_kernel<<<1, 256, 0, stream>>>(row_sum, cnt, out);
}

// Round 13
// 90.988 us; speedup vs baseline: 2.5413x; 1.1994x over previous
//
#include <hip/hip_runtime.h>
#include <math.h>

// ContrastiveLoss round 12 (resubmit after infra failure): round-7 structure
// (best measured, 83us) with the HW-validated round-11 pieces folded in:
//  - splitE node deleted; s_kernel converts E f32->bf16 inline (cold path)
//  - t_kernel epilogue: unique-writer cnt[4096][32], no atomics when 0 positives
//  - no pos_cnt zeroing kernel/work
// 4 nodes: prep -> t -> s(gated) -> finalize.

constexpr int Bn = 4096;
constexpr int Dd = 512;
constexpr int Ff = 128;
constexpr int NB = Bn / 128;                 // 32 row blocks
constexpr int NT = NB * (NB + 1) / 2;        // 528 triangle tiles
constexpr float MARGIN = 0.015625f;          // |T_hh - T_3pass| < 2^-8; 4x safety

typedef __attribute__((ext_vector_type(8))) short bf16x8;
typedef __attribute__((ext_vector_type(4))) float f32x4;

__device__ __forceinline__ ushort f32_to_bf16(float x) {
    unsigned u = __float_as_uint(x);
    unsigned r = (u + 0x7FFFu + ((u >> 16) & 1u)) >> 16;  // RTNE
    return (ushort)r;
}
__device__ __forceinline__ float bf16_to_f32(ushort h) {
    return __uint_as_float(((unsigned)h) << 16);
}

__device__ __forceinline__ void tri_decode(int p, int& bi, int& bj) {
    bi = (int)((sqrtf(8.0f * (float)p + 1.0f) - 1.0f) * 0.5f);
    while ((bi + 1) * (bi + 2) / 2 <= p) ++bi;
    while (bi * (bi + 1) / 2 > p) --bi;
    bj = p - bi * (bi + 1) / 2;
}

// prep: L2-normalize + hi/lo split F (1 wave per row); zero row_sum.
__global__ __launch_bounds__(256) void prep_kernel(const float* __restrict__ sf,
                                                   ushort* __restrict__ fh,
                                                   ushort* __restrict__ fl,
                                                   float* __restrict__ row_sum) {
    if (blockIdx.x < 16) row_sum[blockIdx.x * 256 + threadIdx.x] = 0.0f;

    int row = blockIdx.x * 4 + (threadIdx.x >> 6);
    int lane = threadIdx.x & 63;
    const float2 v = *reinterpret_cast<const float2*>(&sf[(size_t)row * Ff + lane * 2]);
    float ss = v.x * v.x + v.y * v.y;
    #pragma unroll
    for (int off = 32; off; off >>= 1) ss += __shfl_xor(ss, off, 64);
    float inv = 1.0f / fmaxf(sqrtf(ss), 1e-12f);
    float fx = v.x * inv, fy = v.y * inv;
    ushort hx = f32_to_bf16(fx), hy = f32_to_bf16(fy);
    ushort lx = f32_to_bf16(fx - bf16_to_f32(hx));
    ushort ly = f32_to_bf16(fy - bf16_to_f32(hy));
    ushort2 h; h.x = hx; h.y = hy;
    ushort2 l; l.x = lx; l.y = ly;
    *reinterpret_cast<ushort2*>(&fh[(size_t)row * Ff + lane * 2]) = h;
    *reinterpret_cast<ushort2*>(&fl[(size_t)row * Ff + lane * 2]) = l;
}

// Stage a 128x64 bf16 tile via global_load_lds w=16; source pre-swizzled
// (rule #21), reads apply same XOR. Validated rounds 1-7: 0 bank conflicts.
__device__ __forceinline__ void stage_tile(const ushort* __restrict__ src, int stride,
                                           int k0, char* tile, int wave, int lane) {
    #pragma unroll
    for (int q = 0; q < 4; ++q) {
        int boff = wave * 4096 + q * 1024 + lane * 16;
        int row = boff >> 7;
        int cb = (boff & 127) ^ ((row & 7) << 4);
        const ushort* g = src + (size_t)row * stride + k0 + (cb >> 1);
        __builtin_amdgcn_global_load_lds(
            (const __attribute__((address_space(1))) void*)g,
            (__attribute__((address_space(3))) void*)(tile + wave * 4096 + q * 1024),
            16, 0, 0);
    }
}

__device__ __forceinline__ void mfma_step(f32x4 (&acc)[4][4], const char* At, const char* Bt,
                                          int wrow, int wcol, int lane) {
    #pragma unroll
    for (int ks = 0; ks < 2; ++ks) {
        bf16x8 a[4], b[4];
        int koff = ks * 64 + ((lane >> 4) << 4);
        #pragma unroll
        for (int m = 0; m < 4; ++m) {
            int row = wrow + m * 16 + (lane & 15);
            a[m] = *reinterpret_cast<const bf16x8*>(At + row * 128 + (koff ^ ((row & 7) << 4)));
        }
        #pragma unroll
        for (int n = 0; n < 4; ++n) {
            int row = wcol + n * 16 + (lane & 15);
            b[n] = *reinterpret_cast<const bf16x8*>(Bt + row * 128 + (koff ^ ((row & 7) << 4)));
        }
        #pragma unroll
        for (int m = 0; m < 4; ++m)
            #pragma unroll
            for (int n = 0; n < 4; ++n)
                acc[m][n] = __builtin_amdgcn_mfma_f32_16x16x32_bf16(a[m], b[n], acc[m][n], 0, 0, 0);
    }
}

// T kernel: hh pass + margin-gated hl/lh correction (exact decisions).
// Epilogue: LDS count aggregation -> unique-writer cnt[row][otherBlock].
__global__ __launch_bounds__(256) void t_kernel(const ushort* __restrict__ Fh,
                                                const ushort* __restrict__ Fl,
                                                unsigned long long* __restrict__ posbits,
                                                int* __restrict__ cnt) {
    __shared__ __align__(16) char smem[32768];
    __shared__ int flagS;
    __shared__ int rowCnt[128];
    __shared__ int colCnt[128];
    char* At = smem;
    char* Bt = smem + 16384;

    int bi, bj; tri_decode(blockIdx.x, bi, bj);
    const int ti = bi * 128, tj = bj * 128;
    const int tid = threadIdx.x;
    const int lane = tid & 63;
    const int wave = tid >> 6;
    const int wrow = (wave >> 1) * 64;
    const int wcol = (wave & 1) * 64;

    if (tid == 0) flagS = 0;
    if (tid < 128) rowCnt[tid] = 0; else colCnt[tid - 128] = 0;

    f32x4 acc[4][4];
    const f32x4 z4 = {0.0f, 0.0f, 0.0f, 0.0f};
    #pragma unroll
    for (int m = 0; m < 4; ++m)
        #pragma unroll
        for (int n = 0; n < 4; ++n) acc[m][n] = z4;

    // hh pass, K = 128 in two 64-steps.
    for (int k0 = 0; k0 < Ff; k0 += 64) {
        stage_tile(Fh + (size_t)ti * Ff, Ff, k0, At, wave, lane);
        stage_tile(Fh + (size_t)tj * Ff, Ff, k0, Bt, wave, lane);
        __syncthreads();
        mfma_step(acc, At, Bt, wrow, wcol, lane);
        __syncthreads();
    }

    bool nr = false;
    #pragma unroll
    for (int m = 0; m < 4; ++m)
        #pragma unroll
        for (int n = 0; n < 4; ++n)
            #pragma unroll
            for (int r = 0; r < 4; ++r)
                nr |= fabsf(acc[m][n][r] - 0.5f) < MARGIN;
    if (__any(nr)) { if (lane == 0) flagS = 1; }
    __syncthreads();

    if (flagS) {  // cold path: full 3-pass precision for this tile
        for (int k0 = 0; k0 < Ff; k0 += 64) {   // hl
            stage_tile(Fh + (size_t)ti * Ff, Ff, k0, At, wave, lane);
            stage_tile(Fl + (size_t)tj * Ff, Ff, k0, Bt, wave, lane);
            __syncthreads();
            mfma_step(acc, At, Bt, wrow, wcol, lane);
            __syncthreads();
        }
        for (int k0 = 0; k0 < Ff; k0 += 64) {   // lh
            stage_tile(Fl + (size_t)ti * Ff, Ff, k0, At, wave, lane);
            stage_tile(Fh + (size_t)tj * Ff, Ff, k0, Bt, wave, lane);
            __syncthreads();
            mfma_step(acc, At, Bt, wrow, wcol, lane);
            __syncthreads();
        }
    }

    // Positive bits; per-tile cache for the S path.
    unsigned long long pm = 0;
    #pragma unroll
    for (int m = 0; m < 4; ++m)
        #pragma unroll
        for (int n = 0; n < 4; ++n)
            #pragma unroll
            for (int r = 0; r < 4; ++r)
                if (acc[m][n][r] > 0.5f) pm |= 1ull << (m * 16 + n * 4 + r);
    posbits[(size_t)blockIdx.x * 256 + tid] = pm;

    // Count aggregation: LDS atomics only per positive (free when none).
    #pragma unroll
    for (int m = 0; m < 4; ++m) {
        #pragma unroll
        for (int r = 0; r < 4; ++r) {
            int lrow = wrow + m * 16 + ((lane >> 4) << 2) + r;
            int gi = ti + lrow;
            #pragma unroll
            for (int n = 0; n < 4; ++n) {
                int lcol = wcol + n * 16 + (lane & 15);
                int gj = tj + lcol;
                if (gi != gj && ((pm >> (m * 16 + n * 4 + r)) & 1)) {
                    atomicAdd(&rowCnt[lrow], 1);
                    atomicAdd(&colCnt[lcol], 1);
                }
            }
        }
    }
    __syncthreads();
    if (tid < 128) cnt[(size_t)(ti + tid) * NB + bj] = rowCnt[tid];
    else if (bi != bj) cnt[(size_t)(tj + tid - 128) * NB + bi] = colCnt[tid - 128];
}

// Convert+stage one 64-col K-chunk of E rows [rowBase..+128) into hi/lo
// swizzled chunk buffers (cold path only; layout math mirrors stage_tile).
__device__ __forceinline__ void stage_conv(const float* __restrict__ E, int rowBase,
                                           int k0, char* Hbuf, char* Lbuf,
                                           int wave, int lane) {
    #pragma unroll
    for (int q = 0; q < 4; ++q) {
        int boff = wave * 4096 + q * 1024 + lane * 16;
        int row = boff >> 7;
        int d = boff & 127;
        int cb = d ^ ((row & 7) << 4);   // logical col byte (bf16 units)
        const float* src = &E[(size_t)(rowBase + row) * Dd + k0 + (cb >> 1)];
        float4 v0 = *reinterpret_cast<const float4*>(src);
        float4 v1 = *reinterpret_cast<const float4*>(src + 4);
        float c[8] = {v0.x, v0.y, v0.z, v0.w, v1.x, v1.y, v1.z, v1.w};
        bf16x8 hv, lv;
        #pragma unroll
        for (int j = 0; j < 8; ++j) {
            ushort h = f32_to_bf16(c[j]);
            hv[j] = (short)h;
            lv[j] = (short)f32_to_bf16(c[j] - bf16_to_f32(h));
        }
        *reinterpret_cast<bf16x8*>(Hbuf + boff) = hv;
        *reinterpret_cast<bf16x8*>(Lbuf + boff) = lv;
    }
}

// S kernel: gated on cnt row sums; inline E conversion; BCE epilogue.
__global__ __launch_bounds__(256, 2) void s_kernel(
    const float* __restrict__ E, const unsigned long long* __restrict__ posbits,
    const int* __restrict__ cnt, float* __restrict__ row_sum) {
    __shared__ __align__(16) char smem[65536];
    __shared__ int go;
    const int tid = threadIdx.x;
    int bi, bj; tri_decode(blockIdx.x, bi, bj);
    const int ti = bi * 128, tj = bj * 128;

    if (tid == 0) go = 0;
    __syncthreads();
    {
        int r = (tid < 128) ? (ti + tid) : (tj + tid - 128);
        const int4* c4 = reinterpret_cast<const int4*>(&cnt[(size_t)r * NB]);
        int pc = 0;
        #pragma unroll
        for (int q = 0; q < 8; ++q) {
            int4 v = c4[q];
            pc += v.x + v.y + v.z + v.w;
        }
        bool val = (pc > 0) && (pc < Bn - 1);
        if (__any(val)) { if ((tid & 63) == 0) go = 1; }
    }
    __syncthreads();
    if (!go) return;

    const int lane = tid & 63;
    const int wave = tid >> 6;
    const int wrow = (wave >> 1) * 64;
    const int wcol = (wave & 1) * 64;
    char* Ah = smem;
    char* Al = smem + 16384;
    char* Bh = smem + 32768;
    char* Bl = smem + 49152;

    f32x4 acc[4][4];
    const f32x4 z4 = {0.0f, 0.0f, 0.0f, 0.0f};
    #pragma unroll
    for (int m = 0; m < 4; ++m)
        #pragma unroll
        for (int n = 0; n < 4; ++n) acc[m][n] = z4;

    for (int k0 = 0; k0 < Dd; k0 += 64) {
        __syncthreads();   // previous chunk fully consumed
        stage_conv(E, ti, k0, Ah, Al, wave, lane);
        stage_conv(E, tj, k0, Bh, Bl, wave, lane);
        __syncthreads();
        mfma_step(acc, Ah, Bh, wrow, wcol, lane);
        mfma_step(acc, Ah, Bl, wrow, wcol, lane);
        mfma_step(acc, Al, Bh, wrow, wcol, lane);
    }

    unsigned long long pm = posbits[(size_t)blockIdx.x * 256 + tid];
    float colS[4] = {0, 0, 0, 0};
    #pragma unroll
    for (int m = 0; m < 4; ++m) {
        #pragma unroll
        for (int r = 0; r < 4; ++r) {
            float s = 0.0f;
            int gi = ti + wrow + m * 16 + ((lane >> 4) << 2) + r;
            #pragma unroll
            for (int n = 0; n < 4; ++n) {
                int gj = tj + wcol + n * 16 + (lane & 15);
                if (gi != gj) {
                    float S = acc[m][n][r] * 10.0f;            // /TEMPERATURE
                    bool pos = (pm >> (m * 16 + n * 4 + r)) & 1;
                    float x = pos ? -S : S;
                    float sp = fmaxf(x, 0.0f) + log1pf(expf(-fabsf(x)));  // softplus
                    s += sp;
                    if (bi != bj) colS[n] += sp;
                }
            }
            #pragma unroll
            for (int off = 8; off; off >>= 1) s += __shfl_xor(s, off, 16);
            if ((lane & 15) == 0) atomicAdd(&row_sum[gi], s);
        }
    }
    if (bi != bj) {
        #pragma unroll
        for (int n = 0; n < 4; ++n) {
            float s = colS[n];
            s += __shfl_xor(s, 16, 64);
            s += __shfl_xor(s, 32, 64);
            if ((lane >> 4) == 0) {
                int gj = tj + wcol + n * 16 + (lane & 15);
                atomicAdd(&row_sum[gj], s);
            }
        }
    }
}

// finalize: per-row counts from cnt; mean over valid rows.
__global__ __launch_bounds__(256) void finalize_kernel(
    const float* __restrict__ row_sum, const int* __restrict__ cnt,
    float* __restrict__ out) {
    __shared__ float ssum[256];
    __shared__ int scnt[256];
    float ls = 0.0f;
    int lc = 0;
    for (int r = threadIdx.x; r < Bn; r += 256) {
        const int4* c4 = reinterpret_cast<const int4*>(&cnt[(size_t)r * NB]);
        int pc = 0;
        #pragma unroll
        for (int q = 0; q < 8; ++q) {
            int4 v = c4[q];
            pc += v.x + v.y + v.z + v.w;
        }
        if (pc > 0 && pc < Bn - 1) {
            ls += row_sum[r] / (float)(Bn - 1);
            lc += 1;
        }
    }
    ssum[threadIdx.x] = ls;
    scnt[threadIdx.x] = lc;
    __syncthreads();
    for (int s = 128; s; s >>= 1) {
        if (threadIdx.x < s) {
            ssum[threadIdx.x] += ssum[threadIdx.x + s];
            scnt[threadIdx.x] += scnt[threadIdx.x + s];
        }
        __syncthreads();
    }
    if (threadIdx.x == 0) {
        float nv = fmaxf((float)scnt[0], 1.0f);
        out[0] = ssum[0] / nv;
    }
}

extern "C" void kernel_launch(void* const* d_in, const int* in_sizes, int n_in,
                              void* d_out, int out_size, void* d_ws, size_t ws_size,
                              hipStream_t stream) {
    const float* E = (const float*)d_in[0];   // [4096,512] f32
    const float* SF = (const float*)d_in[1];  // [4096,128] f32
    float* out = (float*)d_out;

    // ws: cnt[4096*32] (512K) | row_sum (16K) | fh (1M) | fl (1M) | posbits (1.06M)
    int* cnt = (int*)d_ws;
    float* row_sum = (float*)(cnt + (size_t)Bn * NB);
    ushort* fh = (ushort*)(row_sum + Bn);
    ushort* fl = fh + (size_t)Bn * Ff;
    unsigned long long* posbits =
        (unsigned long long*)(((size_t)(fl + (size_t)Bn * Ff) + 15) & ~15ull);

    prep_kernel<<<Bn / 4, 256, 0, stream>>>(SF, fh, fl, row_sum);
    t_kernel<<<NT, 256, 0, stream>>>(fh, fl, posbits, cnt);
    s_kernel<<<NT, 256, 0, stream>>>(E, posbits, cnt, row_sum);
    finalize_kernel<<<1, 256, 0, stream>>>(row_sum, cnt, out);
}

// Round 15
// 75.087 us; speedup vs baseline: 3.0795x; 1.2118x over previous
//
#include <hip/hip_runtime.h>
#include <math.h>

// ContrastiveLoss round 14 (resubmit after broker timeout): 4-node layout
// (r13) + round-7's cheap pos_cnt gate. t_kernel epilogue: LDS count
// aggregation -> ONE conditional global atomicAdd per row (zero atomics when
// zero positives). s_kernel gates on pos_cnt (4B/thread); finalize reads
// pos_cnt. cnt[4096][32] removed. prep -> t -> s(gated) -> finalize.

constexpr int Bn = 4096;
constexpr int Dd = 512;
constexpr int Ff = 128;
constexpr int NB = Bn / 128;                 // 32 row blocks
constexpr int NT = NB * (NB + 1) / 2;        // 528 triangle tiles
constexpr float MARGIN = 0.015625f;          // |T_hh - T_3pass| < 2^-8; 4x safety

typedef __attribute__((ext_vector_type(8))) short bf16x8;
typedef __attribute__((ext_vector_type(4))) float f32x4;

__device__ __forceinline__ ushort f32_to_bf16(float x) {
    unsigned u = __float_as_uint(x);
    unsigned r = (u + 0x7FFFu + ((u >> 16) & 1u)) >> 16;  // RTNE
    return (ushort)r;
}
__device__ __forceinline__ float bf16_to_f32(ushort h) {
    return __uint_as_float(((unsigned)h) << 16);
}

__device__ __forceinline__ void tri_decode(int p, int& bi, int& bj) {
    bi = (int)((sqrtf(8.0f * (float)p + 1.0f) - 1.0f) * 0.5f);
    while ((bi + 1) * (bi + 2) / 2 <= p) ++bi;
    while (bi * (bi + 1) / 2 > p) --bi;
    bj = p - bi * (bi + 1) / 2;
}

// prep: L2-normalize + hi/lo split F (1 wave per row); zero row_sum+pos_cnt.
__global__ __launch_bounds__(256) void prep_kernel(const float* __restrict__ sf,
                                                   ushort* __restrict__ fh,
                                                   ushort* __restrict__ fl,
                                                   float* __restrict__ row_sum,
                                                   int* __restrict__ pos_cnt) {
    if (blockIdx.x < 16) {
        int i = blockIdx.x * 256 + threadIdx.x;
        row_sum[i] = 0.0f;
        pos_cnt[i] = 0;
    }

    int row = blockIdx.x * 4 + (threadIdx.x >> 6);
    int lane = threadIdx.x & 63;
    const float2 v = *reinterpret_cast<const float2*>(&sf[(size_t)row * Ff + lane * 2]);
    float ss = v.x * v.x + v.y * v.y;
    #pragma unroll
    for (int off = 32; off; off >>= 1) ss += __shfl_xor(ss, off, 64);
    float inv = 1.0f / fmaxf(sqrtf(ss), 1e-12f);
    float fx = v.x * inv, fy = v.y * inv;
    ushort hx = f32_to_bf16(fx), hy = f32_to_bf16(fy);
    ushort lx = f32_to_bf16(fx - bf16_to_f32(hx));
    ushort ly = f32_to_bf16(fy - bf16_to_f32(hy));
    ushort2 h; h.x = hx; h.y = hy;
    ushort2 l; l.x = lx; l.y = ly;
    *reinterpret_cast<ushort2*>(&fh[(size_t)row * Ff + lane * 2]) = h;
    *reinterpret_cast<ushort2*>(&fl[(size_t)row * Ff + lane * 2]) = l;
}

// Stage a 128x64 bf16 tile via global_load_lds w=16; source pre-swizzled
// (rule #21), reads apply same XOR. Validated rounds 1-13: 0 bank conflicts.
__device__ __forceinline__ void stage_tile(const ushort* __restrict__ src, int stride,
                                           int k0, char* tile, int wave, int lane) {
    #pragma unroll
    for (int q = 0; q < 4; ++q) {
        int boff = wave * 4096 + q * 1024 + lane * 16;
        int row = boff >> 7;
        int cb = (boff & 127) ^ ((row & 7) << 4);
        const ushort* g = src + (size_t)row * stride + k0 + (cb >> 1);
        __builtin_amdgcn_global_load_lds(
            (const __attribute__((address_space(1))) void*)g,
            (__attribute__((address_space(3))) void*)(tile + wave * 4096 + q * 1024),
            16, 0, 0);
    }
}

__device__ __forceinline__ void mfma_step(f32x4 (&acc)[4][4], const char* At, const char* Bt,
                                          int wrow, int wcol, int lane) {
    #pragma unroll
    for (int ks = 0; ks < 2; ++ks) {
        bf16x8 a[4], b[4];
        int koff = ks * 64 + ((lane >> 4) << 4);
        #pragma unroll
        for (int m = 0; m < 4; ++m) {
            int row = wrow + m * 16 + (lane & 15);
            a[m] = *reinterpret_cast<const bf16x8*>(At + row * 128 + (koff ^ ((row & 7) << 4)));
        }
        #pragma unroll
        for (int n = 0; n < 4; ++n) {
            int row = wcol + n * 16 + (lane & 15);
            b[n] = *reinterpret_cast<const bf16x8*>(Bt + row * 128 + (koff ^ ((row & 7) << 4)));
        }
        #pragma unroll
        for (int m = 0; m < 4; ++m)
            #pragma unroll
            for (int n = 0; n < 4; ++n)
                acc[m][n] = __builtin_amdgcn_mfma_f32_16x16x32_bf16(a[m], b[n], acc[m][n], 0, 0, 0);
    }
}

// T kernel: hh pass + margin-gated hl/lh correction (exact decisions).
// Epilogue: LDS aggregation -> conditional global atomicAdd to pos_cnt.
__global__ __launch_bounds__(256) void t_kernel(const ushort* __restrict__ Fh,
                                                const ushort* __restrict__ Fl,
                                                unsigned long long* __restrict__ posbits,
                                                int* __restrict__ pos_cnt) {
    __shared__ __align__(16) char smem[32768];
    __shared__ int flagS;
    __shared__ int rowCnt[128];
    __shared__ int colCnt[128];
    char* At = smem;
    char* Bt = smem + 16384;

    int bi, bj; tri_decode(blockIdx.x, bi, bj);
    const int ti = bi * 128, tj = bj * 128;
    const int tid = threadIdx.x;
    const int lane = tid & 63;
    const int wave = tid >> 6;
    const int wrow = (wave >> 1) * 64;
    const int wcol = (wave & 1) * 64;

    if (tid == 0) flagS = 0;
    if (tid < 128) rowCnt[tid] = 0; else colCnt[tid - 128] = 0;

    f32x4 acc[4][4];
    const f32x4 z4 = {0.0f, 0.0f, 0.0f, 0.0f};
    #pragma unroll
    for (int m = 0; m < 4; ++m)
        #pragma unroll
        for (int n = 0; n < 4; ++n) acc[m][n] = z4;

    // hh pass, K = 128 in two 64-steps.
    for (int k0 = 0; k0 < Ff; k0 += 64) {
        stage_tile(Fh + (size_t)ti * Ff, Ff, k0, At, wave, lane);
        stage_tile(Fh + (size_t)tj * Ff, Ff, k0, Bt, wave, lane);
        __syncthreads();
        mfma_step(acc, At, Bt, wrow, wcol, lane);
        __syncthreads();
    }

    bool nr = false;
    #pragma unroll
    for (int m = 0; m < 4; ++m)
        #pragma unroll
        for (int n = 0; n < 4; ++n)
            #pragma unroll
            for (int r = 0; r < 4; ++r)
                nr |= fabsf(acc[m][n][r] - 0.5f) < MARGIN;
    if (__any(nr)) { if (lane == 0) flagS = 1; }
    __syncthreads();

    if (flagS) {  // cold path: full 3-pass precision for this tile
        for (int k0 = 0; k0 < Ff; k0 += 64) {   // hl
            stage_tile(Fh + (size_t)ti * Ff, Ff, k0, At, wave, lane);
            stage_tile(Fl + (size_t)tj * Ff, Ff, k0, Bt, wave, lane);
            __syncthreads();
            mfma_step(acc, At, Bt, wrow, wcol, lane);
            __syncthreads();
        }
        for (int k0 = 0; k0 < Ff; k0 += 64) {   // lh
            stage_tile(Fl + (size_t)ti * Ff, Ff, k0, At, wave, lane);
            stage_tile(Fh + (size_t)tj * Ff, Ff, k0, Bt, wave, lane);
            __syncthreads();
            mfma_step(acc, At, Bt, wrow, wcol, lane);
            __syncthreads();
        }
    }

    // Positive bits; per-tile cache for the S path.
    unsigned long long pm = 0;
    #pragma unroll
    for (int m = 0; m < 4; ++m)
        #pragma unroll
        for (int n = 0; n < 4; ++n)
            #pragma unroll
            for (int r = 0; r < 4; ++r)
                if (acc[m][n][r] > 0.5f) pm |= 1ull << (m * 16 + n * 4 + r);
    posbits[(size_t)blockIdx.x * 256 + tid] = pm;

    // LDS aggregation: atomics fire only per positive (free when none).
    #pragma unroll
    for (int m = 0; m < 4; ++m) {
        #pragma unroll
        for (int r = 0; r < 4; ++r) {
            int lrow = wrow + m * 16 + ((lane >> 4) << 2) + r;
            int gi = ti + lrow;
            #pragma unroll
            for (int n = 0; n < 4; ++n) {
                int lcol = wcol + n * 16 + (lane & 15);
                int gj = tj + lcol;
                if (gi != gj && ((pm >> (m * 16 + n * 4 + r)) & 1)) {
                    atomicAdd(&rowCnt[lrow], 1);
                    atomicAdd(&colCnt[lcol], 1);
                }
            }
        }
    }
    __syncthreads();
    if (tid < 128) {
        int c = rowCnt[tid];
        if (c) atomicAdd(&pos_cnt[ti + tid], c);
    } else if (bi != bj) {
        int c = colCnt[tid - 128];
        if (c) atomicAdd(&pos_cnt[tj + tid - 128], c);
    }
}

// Convert+stage one 64-col K-chunk of E rows [rowBase..+128) into hi/lo
// swizzled chunk buffers (cold path only; layout math mirrors stage_tile).
__device__ __forceinline__ void stage_conv(const float* __restrict__ E, int rowBase,
                                           int k0, char* Hbuf, char* Lbuf,
                                           int wave, int lane) {
    #pragma unroll
    for (int q = 0; q < 4; ++q) {
        int boff = wave * 4096 + q * 1024 + lane * 16;
        int row = boff >> 7;
        int d = boff & 127;
        int cb = d ^ ((row & 7) << 4);   // logical col byte (bf16 units)
        const float* src = &E[(size_t)(rowBase + row) * Dd + k0 + (cb >> 1)];
        float4 v0 = *reinterpret_cast<const float4*>(src);
        float4 v1 = *reinterpret_cast<const float4*>(src + 4);
        float c[8] = {v0.x, v0.y, v0.z, v0.w, v1.x, v1.y, v1.z, v1.w};
        bf16x8 hv, lv;
        #pragma unroll
        for (int j = 0; j < 8; ++j) {
            ushort h = f32_to_bf16(c[j]);
            hv[j] = (short)h;
            lv[j] = (short)f32_to_bf16(c[j] - bf16_to_f32(h));
        }
        *reinterpret_cast<bf16x8*>(Hbuf + boff) = hv;
        *reinterpret_cast<bf16x8*>(Lbuf + boff) = lv;
    }
}

// S kernel: gated on pos_cnt (4B/thread); inline E conversion; BCE epilogue.
__global__ __launch_bounds__(256, 2) void s_kernel(
    const float* __restrict__ E, const unsigned long long* __restrict__ posbits,
    const int* __restrict__ pos_cnt, float* __restrict__ row_sum) {
    __shared__ __align__(16) char smem[65536];
    __shared__ int go;
    const int tid = threadIdx.x;
    int bi, bj; tri_decode(blockIdx.x, bi, bj);
    const int ti = bi * 128, tj = bj * 128;

    if (tid == 0) go = 0;
    __syncthreads();
    {
        int pc = (tid < 128) ? pos_cnt[ti + tid] : pos_cnt[tj + tid - 128];
        bool val = (pc > 0) && (pc < Bn - 1);
        if (__any(val)) { if ((tid & 63) == 0) go = 1; }
    }
    __syncthreads();
    if (!go) return;

    const int lane = tid & 63;
    const int wave = tid >> 6;
    const int wrow = (wave >> 1) * 64;
    const int wcol = (wave & 1) * 64;
    char* Ah = smem;
    char* Al = smem + 16384;
    char* Bh = smem + 32768;
    char* Bl = smem + 49152;

    f32x4 acc[4][4];
    const f32x4 z4 = {0.0f, 0.0f, 0.0f, 0.0f};
    #pragma unroll
    for (int m = 0; m < 4; ++m)
        #pragma unroll
        for (int n = 0; n < 4; ++n) acc[m][n] = z4;

    for (int k0 = 0; k0 < Dd; k0 += 64) {
        __syncthreads();   // previous chunk fully consumed
        stage_conv(E, ti, k0, Ah, Al, wave, lane);
        stage_conv(E, tj, k0, Bh, Bl, wave, lane);
        __syncthreads();
        mfma_step(acc, Ah, Bh, wrow, wcol, lane);
        mfma_step(acc, Ah, Bl, wrow, wcol, lane);
        mfma_step(acc, Al, Bh, wrow, wcol, lane);
    }

    unsigned long long pm = posbits[(size_t)blockIdx.x * 256 + tid];
    float colS[4] = {0, 0, 0, 0};
    #pragma unroll
    for (int m = 0; m < 4; ++m) {
        #pragma unroll
        for (int r = 0; r < 4; ++r) {
            float s = 0.0f;
            int gi = ti + wrow + m * 16 + ((lane >> 4) << 2) + r;
            #pragma unroll
            for (int n = 0; n < 4; ++n) {
                int gj = tj + wcol + n * 16 + (lane & 15);
                if (gi != gj) {
                    float S = acc[m][n][r] * 10.0f;            // /TEMPERATURE
                    bool pos = (pm >> (m * 16 + n * 4 + r)) & 1;
                    float x = pos ? -S : S;
                    float sp = fmaxf(x, 0.0f) + log1pf(expf(-fabsf(x)));  // softplus
                    s += sp;
                    if (bi != bj) colS[n] += sp;
                }
            }
            #pragma unroll
            for (int off = 8; off; off >>= 1) s += __shfl_xor(s, off, 16);
            if ((lane & 15) == 0) atomicAdd(&row_sum[gi], s);
        }
    }
    if (bi != bj) {
        #pragma unroll
        for (int n = 0; n < 4; ++n) {
            float s = colS[n];
            s += __shfl_xor(s, 16, 64);
            s += __shfl_xor(s, 32, 64);
            if ((lane >> 4) == 0) {
                int gj = tj + wcol + n * 16 + (lane & 15);
                atomicAdd(&row_sum[gj], s);
            }
        }
    }
}

// finalize: mean over valid rows (pos_cnt-based, round-7 form).
__global__ __launch_bounds__(256) void finalize_kernel(
    const float* __restrict__ row_sum, const int* __restrict__ pos_cnt,
    float* __restrict__ out) {
    __shared__ float ssum[256];
    __shared__ int scnt[256];
    float ls = 0.0f;
    int lc = 0;
    for (int r = threadIdx.x; r < Bn; r += 256) {
        int pz = pos_cnt[r];
        if (pz > 0 && pz < Bn - 1) {
            ls += row_sum[r] / (float)(Bn - 1);
            lc += 1;
        }
    }
    ssum[threadIdx.x] = ls;
    scnt[threadIdx.x] = lc;
    __syncthreads();
    for (int s = 128; s; s >>= 1) {
        if (threadIdx.x < s) {
            ssum[threadIdx.x] += ssum[threadIdx.x + s];
            scnt[threadIdx.x] += scnt[threadIdx.x + s];
        }
        __syncthreads();
    }
    if (threadIdx.x == 0) {
        float nv = fmaxf((float)scnt[0], 1.0f);
        out[0] = ssum[0] / nv;
    }
}

extern "C" void kernel_launch(void* const* d_in, const int* in_sizes, int n_in,
                              void* d_out, int out_size, void* d_ws, size_t ws_size,
                              hipStream_t stream) {
    const float* E = (const float*)d_in[0];   // [4096,512] f32
    const float* SF = (const float*)d_in[1];  // [4096,128] f32
    float* out = (float*)d_out;

    // ws: row_sum(16K) | pos_cnt(16K) | fh(1M) | fl(1M) | posbits(1.06M)
    float* row_sum = (float*)d_ws;
    int* pos_cnt = (int*)(row_sum + Bn);
    ushort* fh = (ushort*)(pos_cnt + Bn);
    ushort* fl = fh + (size_t)Bn * Ff;
    unsigned long long* posbits =
        (unsigned long long*)(((size_t)(fl + (size_t)Bn * Ff) + 15) & ~15ull);

    prep_kernel<<<Bn / 4, 256, 0, stream>>>(SF, fh, fl, row_sum, pos_cnt);
    t_kernel<<<NT, 256, 0, stream>>>(fh, fl, posbits, pos_cnt);
    s_kernel<<<NT, 256, 0, stream>>>(E, posbits, pos_cnt, row_sum);
    finalize_kernel<<<1, 256, 0, stream>>>(row_sum, pos_cnt, out);
}